// Round 1
// baseline (535.154 us; speedup 1.0000x reference)
//
#include <hip/hip_runtime.h>
#include <stdint.h>

typedef __bf16 bf16x8 __attribute__((ext_vector_type(8)));
typedef float f32x4 __attribute__((ext_vector_type(4)));
typedef unsigned short u16;

__device__ __forceinline__ u16 f2bf(float f) {
  union { float f; unsigned u; } v; v.f = f;
  return (u16)((v.u + 0x7fffu + ((v.u >> 16) & 1u)) >> 16);
}

#define GLOAD_LDS16(gp, lp)                                                       \
  __builtin_amdgcn_global_load_lds((__attribute__((address_space(1))) void*)(gp), \
                                   (__attribute__((address_space(3))) void*)(lp), \
                                   16, 0, 0)

// ---------------- f32 -> bf16, vectorized ----------------
__global__ void k_cvt_bf16(const float* __restrict__ in, u16* __restrict__ out, int n4) {
  int i = blockIdx.x * blockDim.x + threadIdx.x;
  if (i >= n4) return;
  float4 v = ((const float4*)in)[i];
  ushort4 o;
  o.x = f2bf(v.x); o.y = f2bf(v.y); o.z = f2bf(v.z); o.w = f2bf(v.w);
  ((ushort4*)out)[i] = o;
}

// ---------------- w[K][N] f32 -> wt[N][K] bf16 (tiled transpose) ----------------
__global__ void k_transpose_bf16(const float* __restrict__ w, u16* __restrict__ wt,
                                 int K, int N) {
  __shared__ u16 t[32][33];
  int n0 = blockIdx.x * 32, k0 = blockIdx.y * 32;
  int tx = threadIdx.x & 31, ty = threadIdx.x >> 5;  // ty 0..7
#pragma unroll
  for (int j = 0; j < 4; ++j) {
    int r = ty + j * 8;
    t[r][tx] = f2bf(w[(size_t)(k0 + r) * N + n0 + tx]);
  }
  __syncthreads();
#pragma unroll
  for (int j = 0; j < 4; ++j) {
    int r = ty + j * 8;
    wt[(size_t)(n0 + r) * K + k0 + tx] = t[tx][r];
  }
}

// ---------------- bt-GEMM: C[M][N] = A[M][K]*Bt[N][K]^T + bias ----------------
// MODE 0: QKV epilogue -> scatter Q(,*0.125)/K/[B*H][S][DK], Vt [B*H][DK][S]
// MODE 1: f32 out + bias
template <int MODE>
__global__ void __launch_bounds__(256, 2)
k_gemm_bt(const u16* __restrict__ A, const u16* __restrict__ Bt,
          const float* __restrict__ bias, u16* __restrict__ outQ,
          u16* __restrict__ outK, u16* __restrict__ outVt,
          float* __restrict__ outF, int Kdim, int Ncols) {
  __shared__ u16 Asq[128 * 64];
  __shared__ u16 Bsq[128 * 64];
  const int tid = threadIdx.x;
  const int lane = tid & 63;
  const int wv = tid >> 6;
  const int g = lane >> 4;
  const int lr = lane & 15;
  const int wr = wv >> 1, wc = wv & 1;
  const int row0 = blockIdx.y * 128;
  const int col0 = blockIdx.x * 128;

  const f32x4 fzero = {0.f, 0.f, 0.f, 0.f};
  f32x4 acc[4][4];
#pragma unroll
  for (int m = 0; m < 4; ++m)
#pragma unroll
    for (int n = 0; n < 4; ++n) acc[m][n] = fzero;

  const u16* Arow = A + (size_t)row0 * Kdim;
  const u16* Brow = Bt + (size_t)col0 * Kdim;

  for (int kt = 0; kt < Kdim; kt += 64) {
    // stage 128x64 bf16 tiles; LDS linear, global source pre-swizzled (u ^ row&7)
#pragma unroll
    for (int j = 0; j < 4; ++j) {
      int unit = j * 256 + wv * 64 + lane;
      int r = unit >> 3, u = unit & 7;
      int ug = u ^ (r & 7);
      GLOAD_LDS16(Arow + (size_t)r * Kdim + kt + ug * 8,
                  &Asq[(size_t)(j * 256 + wv * 64) * 8]);
      GLOAD_LDS16(Brow + (size_t)r * Kdim + kt + ug * 8,
                  &Bsq[(size_t)(j * 256 + wv * 64) * 8]);
    }
    __syncthreads();
#pragma unroll
    for (int kc = 0; kc < 2; ++kc) {
      bf16x8 af[4], bfr[4];
#pragma unroll
      for (int m = 0; m < 4; ++m) {
        int r = wr * 64 + m * 16 + lr;
        int u = (kc * 4 + g) ^ (r & 7);
        af[m] = *(const bf16x8*)((const char*)Asq + r * 128 + u * 16);
      }
#pragma unroll
      for (int n = 0; n < 4; ++n) {
        int r = wc * 64 + n * 16 + lr;
        int u = (kc * 4 + g) ^ (r & 7);
        bfr[n] = *(const bf16x8*)((const char*)Bsq + r * 128 + u * 16);
      }
#pragma unroll
      for (int m = 0; m < 4; ++m)
#pragma unroll
        for (int n = 0; n < 4; ++n)
          acc[m][n] = __builtin_amdgcn_mfma_f32_16x16x32_bf16(af[m], bfr[n],
                                                              acc[m][n], 0, 0, 0);
    }
    __syncthreads();
  }

  // epilogue: C/D layout col = lane&15, row = 4*(lane>>4)+reg
#pragma unroll
  for (int n = 0; n < 4; ++n) {
    int e = col0 + wc * 64 + n * 16 + lr;
    float bv = bias[e];
    if (MODE == 0) {
      int part = e >> 10;
      int d = e & 1023;
      int hh = d >> 6;
      int dk = d & 63;
#pragma unroll
      for (int m = 0; m < 4; ++m) {
        int tbase = row0 + wr * 64 + m * 16 + g * 4;
        int bb = tbase >> 11;
        int s = tbase & 2047;
        size_t bh = (size_t)((bb << 4) + hh);
        if (part == 2) {
          ushort4 pk;
          pk.x = f2bf(acc[m][n][0] + bv);
          pk.y = f2bf(acc[m][n][1] + bv);
          pk.z = f2bf(acc[m][n][2] + bv);
          pk.w = f2bf(acc[m][n][3] + bv);
          *(ushort4*)(outVt + (bh * 64 + dk) * 2048 + s) = pk;
        } else {
#pragma unroll
          for (int i = 0; i < 4; ++i) {
            float val = acc[m][n][i] + bv;
            size_t off = (bh * 2048 + (size_t)(s + i)) * 64 + dk;
            if (part == 0)
              outQ[off] = f2bf(val * 0.125f);
            else
              outK[off] = f2bf(val);
          }
        }
      }
    } else {
#pragma unroll
      for (int m = 0; m < 4; ++m)
#pragma unroll
        for (int i = 0; i < 4; ++i) {
          int t = row0 + wr * 64 + m * 16 + g * 4 + i;
          outF[(size_t)t * Ncols + e] = acc[m][n][i] + bv;
        }
    }
  }
}

// ---------------- causal flash attention ----------------
// grid (S/64, B*H); 4 waves/block, wave owns 16 q-rows; KV tiles of 64.
// Q [BH][S][64] (pre-scaled), K [BH][S][64], Vt [BH][64][S]; out attn[B,S,D] bf16
__global__ void __launch_bounds__(256, 2)
k_flash(const u16* __restrict__ Qg, const u16* __restrict__ Kg,
        const u16* __restrict__ Vtg, u16* __restrict__ attn) {
  __shared__ u16 P_lds[4][16][72];  // 72 = 64 + 8 pad -> 144B row stride, conflict-free b128
  const int tid = threadIdx.x;
  const int lane = tid & 63;
  const int wv = tid >> 6;
  const int g = lane >> 4;
  const int lr = lane & 15;
  const int qt = blockIdx.x;
  const int bh = blockIdx.y;

  const u16* Qb = Qg + (size_t)bh * 2048 * 64;
  const u16* Kb = Kg + (size_t)bh * 2048 * 64;
  const u16* Vb = Vtg + (size_t)bh * 64 * 2048;

  const int q0 = qt * 64 + wv * 16;

  bf16x8 qf[2];
#pragma unroll
  for (int kc = 0; kc < 2; ++kc)
    qf[kc] = *(const bf16x8*)(Qb + (size_t)(q0 + lr) * 64 + kc * 32 + g * 8);

  const f32x4 fzero = {0.f, 0.f, 0.f, 0.f};
  f32x4 o[4];
#pragma unroll
  for (int cf = 0; cf < 4; ++cf) o[cf] = fzero;
  float mrow[4] = {-1e30f, -1e30f, -1e30f, -1e30f};
  float lrow[4] = {0.f, 0.f, 0.f, 0.f};

  for (int kt = 0; kt <= qt; ++kt) {
    const int kbase = kt * 64;
    f32x4 s[4];
#pragma unroll
    for (int cf = 0; cf < 4; ++cf) {
      s[cf] = fzero;
#pragma unroll
      for (int kc = 0; kc < 2; ++kc) {
        bf16x8 kf = *(const bf16x8*)(Kb + (size_t)(kbase + cf * 16 + lr) * 64 +
                                     kc * 32 + g * 8);
        s[cf] = __builtin_amdgcn_mfma_f32_16x16x32_bf16(qf[kc], kf, s[cf], 0, 0, 0);
      }
    }
    if (kbase + 63 > q0) {  // diagonal tile: elementwise causal mask
#pragma unroll
      for (int cf = 0; cf < 4; ++cf) {
        int col = kbase + cf * 16 + lr;
#pragma unroll
        for (int i = 0; i < 4; ++i) {
          int row = q0 + g * 4 + i;
          if (col > row) s[cf][i] = -1e30f;
        }
      }
    }
    // online softmax, rows r = g*4+i live in reg i across the 16 lanes of group g
    float alpha[4];
#pragma unroll
    for (int i = 0; i < 4; ++i) {
      float tm = fmaxf(fmaxf(s[0][i], s[1][i]), fmaxf(s[2][i], s[3][i]));
      tm = fmaxf(tm, __shfl_xor(tm, 1));
      tm = fmaxf(tm, __shfl_xor(tm, 2));
      tm = fmaxf(tm, __shfl_xor(tm, 4));
      tm = fmaxf(tm, __shfl_xor(tm, 8));
      float mn = fmaxf(mrow[i], tm);
      alpha[i] = __expf(mrow[i] - mn);
      mrow[i] = mn;
    }
#pragma unroll
    for (int cf = 0; cf < 4; ++cf)
#pragma unroll
      for (int i = 0; i < 4; ++i) s[cf][i] = __expf(s[cf][i] - mrow[i]);
#pragma unroll
    for (int i = 0; i < 4; ++i) {
      float rs = s[0][i] + s[1][i] + s[2][i] + s[3][i];
      rs += __shfl_xor(rs, 1);
      rs += __shfl_xor(rs, 2);
      rs += __shfl_xor(rs, 4);
      rs += __shfl_xor(rs, 8);
      lrow[i] = lrow[i] * alpha[i] + rs;
    }
#pragma unroll
    for (int cf = 0; cf < 4; ++cf)
#pragma unroll
      for (int i = 0; i < 4; ++i) o[cf][i] *= alpha[i];
    // P -> LDS (per-wave private region; C-layout -> A-frag layout)
#pragma unroll
    for (int cf = 0; cf < 4; ++cf)
#pragma unroll
      for (int i = 0; i < 4; ++i)
        P_lds[wv][g * 4 + i][cf * 16 + lr] = f2bf(s[cf][i]);
    // PV: A = P[16][64], B = V[64][dk] read as Vt rows (contiguous 16B)
#pragma unroll
    for (int kc = 0; kc < 2; ++kc) {
      bf16x8 pa = *(const bf16x8*)((const char*)&P_lds[wv][0][0] + lr * 144 +
                                   kc * 64 + g * 16);
#pragma unroll
      for (int cf = 0; cf < 4; ++cf) {
        bf16x8 vf = *(const bf16x8*)(Vb + (size_t)(cf * 16 + lr) * 2048 + kbase +
                                     kc * 32 + g * 8);
        o[cf] = __builtin_amdgcn_mfma_f32_16x16x32_bf16(pa, vf, o[cf], 0, 0, 0);
      }
    }
  }
  const int bb = bh >> 4, hh = bh & 15;
#pragma unroll
  for (int cf = 0; cf < 4; ++cf)
#pragma unroll
    for (int i = 0; i < 4; ++i) {
      float v = o[cf][i] / lrow[i];
      int row = q0 + g * 4 + i;
      attn[((size_t)(bb * 2048 + row)) * 1024 + hh * 64 + cf * 16 + lr] = f2bf(v);
    }
}

extern "C" void kernel_launch(void* const* d_in, const int* in_sizes, int n_in,
                              void* d_out, int out_size, void* d_ws, size_t ws_size,
                              hipStream_t stream) {
  const float* x      = (const float*)d_in[0];
  // d_in[1] = mask: exactly causal triu(-1e9) -> applied analytically, not read
  const float* w_qkv  = (const float*)d_in[2];
  const float* b_qkv  = (const float*)d_in[3];
  const float* w_head = (const float*)d_in[4];
  const float* b_head = (const float*)d_in[5];
  float* out = (float*)d_out;

  u16* Xb    = (u16*)d_ws;                      // 8192*1024 bf16
  u16* Wqkvt = Xb + (size_t)8192 * 1024;        // 3072*1024
  u16* Wht   = Wqkvt + (size_t)3072 * 1024;     // 1024*1024
  u16* Qw    = Wht + (size_t)1024 * 1024;       // 64*2048*64
  u16* Kw    = Qw + (size_t)64 * 2048 * 64;
  u16* Vtw   = Kw + (size_t)64 * 2048 * 64;
  u16* Attn  = Xb;  // alias: Xb dead after GEMM1

  k_cvt_bf16<<<8192, 256, 0, stream>>>(x, Xb, (8192 * 1024) / 4);
  k_transpose_bf16<<<dim3(96, 32), 256, 0, stream>>>(w_qkv, Wqkvt, 1024, 3072);
  k_transpose_bf16<<<dim3(32, 32), 256, 0, stream>>>(w_head, Wht, 1024, 1024);
  k_gemm_bt<0><<<dim3(24, 64), 256, 0, stream>>>(Xb, Wqkvt, b_qkv, Qw, Kw, Vtw,
                                                 nullptr, 1024, 3072);
  k_flash<<<dim3(32, 64), 256, 0, stream>>>(Qw, Kw, Vtw, Attn);
  k_gemm_bt<1><<<dim3(8, 64), 256, 0, stream>>>(Attn, Wht, b_head, nullptr, nullptr,
                                                nullptr, out, 1024, 1024);
}

// Round 2
// 221.290 us; speedup vs baseline: 2.4183x; 2.4183x over previous
//
#include <hip/hip_runtime.h>
#include <stdint.h>

typedef __bf16 bf16x8 __attribute__((ext_vector_type(8)));
typedef float f32x4 __attribute__((ext_vector_type(4)));
typedef unsigned short u16;

__device__ __forceinline__ u16 f2bf(float f) {
  union { float f; unsigned u; } v; v.f = f;
  return (u16)((v.u + 0x7fffu + ((v.u >> 16) & 1u)) >> 16);
}

#define GLOAD_LDS16(gp, lp)                                                       \
  __builtin_amdgcn_global_load_lds((__attribute__((address_space(1))) void*)(gp), \
                                   (__attribute__((address_space(3))) void*)(lp), \
                                   16, 0, 0)

// ---------------- f32 -> bf16, vectorized ----------------
__global__ void k_cvt_bf16(const float* __restrict__ in, u16* __restrict__ out, int n4) {
  int i = blockIdx.x * blockDim.x + threadIdx.x;
  if (i >= n4) return;
  float4 v = ((const float4*)in)[i];
  ushort4 o;
  o.x = f2bf(v.x); o.y = f2bf(v.y); o.z = f2bf(v.z); o.w = f2bf(v.w);
  ((ushort4*)out)[i] = o;
}

// ---------------- w[K][N] f32 -> wt[N][K] bf16 (tiled transpose) ----------------
__global__ void k_transpose_bf16(const float* __restrict__ w, u16* __restrict__ wt,
                                 int K, int N) {
  __shared__ u16 t[32][33];
  int n0 = blockIdx.x * 32, k0 = blockIdx.y * 32;
  int tx = threadIdx.x & 31, ty = threadIdx.x >> 5;  // ty 0..7
#pragma unroll
  for (int j = 0; j < 4; ++j) {
    int r = ty + j * 8;
    t[r][tx] = f2bf(w[(size_t)(k0 + r) * N + n0 + tx]);
  }
  __syncthreads();
#pragma unroll
  for (int j = 0; j < 4; ++j) {
    int r = ty + j * 8;
    wt[(size_t)(n0 + r) * K + k0 + tx] = t[tx][r];
  }
}

// ---------------- bt-GEMM: C[M][N] = A[M][K]*Bt[N][K]^T + bias ----------------
// MODE 0: QKV epilogue -> scatter Q(,*0.125)/K/[B*H][S][DK], Vt [B*H][DK][S]
// MODE 1: f32 out + bias
template <int MODE>
__global__ void __launch_bounds__(256, 2)
k_gemm_bt(const u16* __restrict__ A, const u16* __restrict__ Bt,
          const float* __restrict__ bias, u16* __restrict__ outQ,
          u16* __restrict__ outK, u16* __restrict__ outVt,
          float* __restrict__ outF, int Kdim, int Ncols) {
  __shared__ u16 Asq[128 * 64];
  __shared__ u16 Bsq[128 * 64];
  const int tid = threadIdx.x;
  const int lane = tid & 63;
  const int wv = tid >> 6;
  const int g = lane >> 4;
  const int lr = lane & 15;
  const int wr = wv >> 1, wc = wv & 1;
  const int row0 = blockIdx.y * 128;
  const int col0 = blockIdx.x * 128;

  const f32x4 fzero = {0.f, 0.f, 0.f, 0.f};
  f32x4 acc[4][4];
#pragma unroll
  for (int m = 0; m < 4; ++m)
#pragma unroll
    for (int n = 0; n < 4; ++n) acc[m][n] = fzero;

  const u16* Arow = A + (size_t)row0 * Kdim;
  const u16* Brow = Bt + (size_t)col0 * Kdim;

  for (int kt = 0; kt < Kdim; kt += 64) {
#pragma unroll
    for (int j = 0; j < 4; ++j) {
      int unit = j * 256 + wv * 64 + lane;
      int r = unit >> 3, u = unit & 7;
      int ug = u ^ (r & 7);
      GLOAD_LDS16(Arow + (size_t)r * Kdim + kt + ug * 8,
                  &Asq[(size_t)(j * 256 + wv * 64) * 8]);
      GLOAD_LDS16(Brow + (size_t)r * Kdim + kt + ug * 8,
                  &Bsq[(size_t)(j * 256 + wv * 64) * 8]);
    }
    __syncthreads();
#pragma unroll
    for (int kc = 0; kc < 2; ++kc) {
      bf16x8 af[4], bfr[4];
#pragma unroll
      for (int m = 0; m < 4; ++m) {
        int r = wr * 64 + m * 16 + lr;
        int u = (kc * 4 + g) ^ (r & 7);
        af[m] = *(const bf16x8*)((const char*)Asq + r * 128 + u * 16);
      }
#pragma unroll
      for (int n = 0; n < 4; ++n) {
        int r = wc * 64 + n * 16 + lr;
        int u = (kc * 4 + g) ^ (r & 7);
        bfr[n] = *(const bf16x8*)((const char*)Bsq + r * 128 + u * 16);
      }
#pragma unroll
      for (int m = 0; m < 4; ++m)
#pragma unroll
        for (int n = 0; n < 4; ++n)
          acc[m][n] = __builtin_amdgcn_mfma_f32_16x16x32_bf16(af[m], bfr[n],
                                                              acc[m][n], 0, 0, 0);
    }
    __syncthreads();
  }

  // epilogue: C/D layout col = lane&15, row = 4*(lane>>4)+reg
#pragma unroll
  for (int n = 0; n < 4; ++n) {
    int e = col0 + wc * 64 + n * 16 + lr;
    float bv = bias[e];
    if (MODE == 0) {
      int part = e >> 10;
      int d = e & 1023;
      int hh = d >> 6;
      int dk = d & 63;
#pragma unroll
      for (int m = 0; m < 4; ++m) {
        int tbase = row0 + wr * 64 + m * 16 + g * 4;
        int bb = tbase >> 11;
        int s = tbase & 2047;
        size_t bh = (size_t)((bb << 4) + hh);
        if (part == 2) {
          ushort4 pk;
          pk.x = f2bf(acc[m][n][0] + bv);
          pk.y = f2bf(acc[m][n][1] + bv);
          pk.z = f2bf(acc[m][n][2] + bv);
          pk.w = f2bf(acc[m][n][3] + bv);
          *(ushort4*)(outVt + (bh * 64 + dk) * 2048 + s) = pk;
        } else {
#pragma unroll
          for (int i = 0; i < 4; ++i) {
            float val = acc[m][n][i] + bv;
            size_t off = (bh * 2048 + (size_t)(s + i)) * 64 + dk;
            if (part == 0)
              outQ[off] = f2bf(val * 0.125f);
            else
              outK[off] = f2bf(val);
          }
        }
      }
    } else {
#pragma unroll
      for (int m = 0; m < 4; ++m)
#pragma unroll
        for (int i = 0; i < 4; ++i) {
          int t = row0 + wr * 64 + m * 16 + g * 4 + i;
          outF[(size_t)t * Ncols + e] = acc[m][n][i] + bv;
        }
    }
  }
}

// ---------------- causal flash attention, LDS-staged double-buffered ----------------
// grid 1024: block handles q-tiles (qa, 31-qa) of one (b,h) -> 33 tile-computes each.
// Q [BH][S][64] (pre-scaled), K [BH][S][64], Vt [BH][64][S]; out attn[B,S,D] bf16.
// K/V tiles 64x64 bf16 staged in LDS (XOR-swizzled via pre-swizzled source),
// double-buffered, prefetch issued before compute.

__device__ __forceinline__ void stage_kv(const u16* __restrict__ Kb,
                                         const u16* __restrict__ Vb, int kbase,
                                         u16* Kbuf, u16* Vbuf, int wv, int lane) {
#pragma unroll
  for (int j = 0; j < 2; ++j) {
    int unit = j * 256 + wv * 64 + lane;
    int r = unit >> 3, u = unit & 7;
    int ug = u ^ (r & 7);
    GLOAD_LDS16(Kb + (size_t)(kbase + r) * 64 + ug * 8, Kbuf + (j * 256 + wv * 64) * 8);
    GLOAD_LDS16(Vb + (size_t)r * 2048 + kbase + ug * 8, Vbuf + (j * 256 + wv * 64) * 8);
  }
}

__device__ __forceinline__ void attn_tile(const u16* Kbuf, const u16* Vbuf, u16* Pw,
                                          const bf16x8* qf, f32x4* o, float* mrow,
                                          float* lrow, int q0, int kbase, int lr,
                                          int g) {
  const f32x4 fzero = {0.f, 0.f, 0.f, 0.f};
  f32x4 s[4];
  __builtin_amdgcn_s_setprio(1);
#pragma unroll
  for (int cf = 0; cf < 4; ++cf) {
    s[cf] = fzero;
#pragma unroll
    for (int kc = 0; kc < 2; ++kc) {
      int r = cf * 16 + lr;
      int us = (kc * 4 + g) ^ (r & 7);
      bf16x8 kf = *(const bf16x8*)(Kbuf + r * 64 + us * 8);
      s[cf] = __builtin_amdgcn_mfma_f32_16x16x32_bf16(qf[kc], kf, s[cf], 0, 0, 0);
    }
  }
  __builtin_amdgcn_s_setprio(0);
  if (kbase + 63 > q0) {  // diagonal tile: elementwise causal mask
#pragma unroll
    for (int cf = 0; cf < 4; ++cf) {
      int col = kbase + cf * 16 + lr;
#pragma unroll
      for (int i = 0; i < 4; ++i) {
        int row = q0 + g * 4 + i;
        if (col > row) s[cf][i] = -1e30f;
      }
    }
  }
  float alpha[4];
#pragma unroll
  for (int i = 0; i < 4; ++i) {
    float tm = fmaxf(fmaxf(s[0][i], s[1][i]), fmaxf(s[2][i], s[3][i]));
    tm = fmaxf(tm, __shfl_xor(tm, 1));
    tm = fmaxf(tm, __shfl_xor(tm, 2));
    tm = fmaxf(tm, __shfl_xor(tm, 4));
    tm = fmaxf(tm, __shfl_xor(tm, 8));
    float mn = fmaxf(mrow[i], tm);
    alpha[i] = __expf(mrow[i] - mn);
    mrow[i] = mn;
  }
#pragma unroll
  for (int cf = 0; cf < 4; ++cf)
#pragma unroll
    for (int i = 0; i < 4; ++i) s[cf][i] = __expf(s[cf][i] - mrow[i]);
#pragma unroll
  for (int i = 0; i < 4; ++i) {
    float rs = s[0][i] + s[1][i] + s[2][i] + s[3][i];
    rs += __shfl_xor(rs, 1);
    rs += __shfl_xor(rs, 2);
    rs += __shfl_xor(rs, 4);
    rs += __shfl_xor(rs, 8);
    lrow[i] = lrow[i] * alpha[i] + rs;
  }
#pragma unroll
  for (int cf = 0; cf < 4; ++cf)
#pragma unroll
    for (int i = 0; i < 4; ++i) o[cf][i] *= alpha[i];
  // P -> LDS (per-wave region [16][64], XOR-swizzled units: un = (c>>3) ^ (row&7))
#pragma unroll
  for (int cf = 0; cf < 4; ++cf)
#pragma unroll
    for (int i = 0; i < 4; ++i) {
      int row = g * 4 + i;
      int un = (cf * 2 + (lr >> 3)) ^ (row & 7);
      Pw[row * 64 + un * 8 + (lr & 7)] = f2bf(s[cf][i]);
    }
  __builtin_amdgcn_s_setprio(1);
#pragma unroll
  for (int kc = 0; kc < 2; ++kc) {
    int up = (kc * 4 + g) ^ (lr & 7);
    bf16x8 pa = *(const bf16x8*)(Pw + lr * 64 + up * 8);
#pragma unroll
    for (int cf = 0; cf < 4; ++cf) {
      int r = cf * 16 + lr;
      int us = (kc * 4 + g) ^ (r & 7);
      bf16x8 vf = *(const bf16x8*)(Vbuf + r * 64 + us * 8);
      o[cf] = __builtin_amdgcn_mfma_f32_16x16x32_bf16(pa, vf, o[cf], 0, 0, 0);
    }
  }
  __builtin_amdgcn_s_setprio(0);
}

__global__ void __launch_bounds__(256, 4)
k_flash(const u16* __restrict__ Qg, const u16* __restrict__ Kg,
        const u16* __restrict__ Vtg, u16* __restrict__ attn) {
  __shared__ u16 KV[2][2][4096];       // [buf][K/V][64 rows x 64 cols swizzled]
  __shared__ u16 P_lds[4][16][64];     // per-wave P, XOR-swizzled
  const int tid = threadIdx.x;
  const int lane = tid & 63;
  const int wv = tid >> 6;
  const int g = lane >> 4;
  const int lr = lane & 15;

  // XCD-chunked bijective swizzle: 1024 blocks, 8 XCDs, 128/chunk
  const int flat = blockIdx.x;
  const int swz = (flat & 7) * 128 + (flat >> 3);
  const int qa_t = swz & 15;           // 0..15
  const int qb_t = 31 - qa_t;          // 16..31
  const int bh = swz >> 4;

  const u16* Qb = Qg + (size_t)bh * 2048 * 64;
  const u16* Kb = Kg + (size_t)bh * 2048 * 64;
  const u16* Vb = Vtg + (size_t)bh * 64 * 2048;
  u16* Pw = &P_lds[wv][0][0];

  const int q0a = qa_t * 64 + wv * 16;
  const int q0b = qb_t * 64 + wv * 16;

  bf16x8 qfa[2], qfb[2];
#pragma unroll
  for (int kc = 0; kc < 2; ++kc) {
    qfa[kc] = *(const bf16x8*)(Qb + (size_t)(q0a + lr) * 64 + kc * 32 + g * 8);
    qfb[kc] = *(const bf16x8*)(Qb + (size_t)(q0b + lr) * 64 + kc * 32 + g * 8);
  }

  const f32x4 fzero = {0.f, 0.f, 0.f, 0.f};
  f32x4 oa[4], ob[4];
#pragma unroll
  for (int cf = 0; cf < 4; ++cf) { oa[cf] = fzero; ob[cf] = fzero; }
  float mra[4] = {-1e30f, -1e30f, -1e30f, -1e30f};
  float lra[4] = {0.f, 0.f, 0.f, 0.f};
  float mrb[4] = {-1e30f, -1e30f, -1e30f, -1e30f};
  float lrb[4] = {0.f, 0.f, 0.f, 0.f};

  stage_kv(Kb, Vb, 0, &KV[0][0][0], &KV[0][1][0], wv, lane);
  __syncthreads();

  for (int kt = 0; kt <= qb_t; ++kt) {
    const int nb = kt & 1;
    const u16* Kbuf = &KV[nb][0][0];
    const u16* Vbuf = &KV[nb][1][0];
    if (kt < qb_t)
      stage_kv(Kb, Vb, (kt + 1) * 64, &KV[nb ^ 1][0][0], &KV[nb ^ 1][1][0], wv, lane);
    attn_tile(Kbuf, Vbuf, Pw, qfb, ob, mrb, lrb, q0b, kt * 64, lr, g);
    if (kt <= qa_t)
      attn_tile(Kbuf, Vbuf, Pw, qfa, oa, mra, lra, q0a, kt * 64, lr, g);
    __syncthreads();
  }

  const int bb = bh >> 4, hh = bh & 15;
#pragma unroll
  for (int cf = 0; cf < 4; ++cf)
#pragma unroll
    for (int i = 0; i < 4; ++i) {
      int rowA = q0a + g * 4 + i;
      int rowB = q0b + g * 4 + i;
      attn[((size_t)(bb * 2048 + rowA)) * 1024 + hh * 64 + cf * 16 + lr] =
          f2bf(oa[cf][i] / lra[i]);
      attn[((size_t)(bb * 2048 + rowB)) * 1024 + hh * 64 + cf * 16 + lr] =
          f2bf(ob[cf][i] / lrb[i]);
    }
}

extern "C" void kernel_launch(void* const* d_in, const int* in_sizes, int n_in,
                              void* d_out, int out_size, void* d_ws, size_t ws_size,
                              hipStream_t stream) {
  const float* x      = (const float*)d_in[0];
  // d_in[1] = mask: exactly causal triu(-1e9) -> applied analytically, not read
  const float* w_qkv  = (const float*)d_in[2];
  const float* b_qkv  = (const float*)d_in[3];
  const float* w_head = (const float*)d_in[4];
  const float* b_head = (const float*)d_in[5];
  float* out = (float*)d_out;

  u16* Xb    = (u16*)d_ws;                      // 8192*1024 bf16
  u16* Wqkvt = Xb + (size_t)8192 * 1024;        // 3072*1024
  u16* Wht   = Wqkvt + (size_t)3072 * 1024;     // 1024*1024
  u16* Qw    = Wht + (size_t)1024 * 1024;       // 64*2048*64
  u16* Kw    = Qw + (size_t)64 * 2048 * 64;
  u16* Vtw   = Kw + (size_t)64 * 2048 * 64;
  u16* Attn  = Xb;  // alias: Xb dead after GEMM1

  k_cvt_bf16<<<8192, 256, 0, stream>>>(x, Xb, (8192 * 1024) / 4);
  k_transpose_bf16<<<dim3(96, 32), 256, 0, stream>>>(w_qkv, Wqkvt, 1024, 3072);
  k_transpose_bf16<<<dim3(32, 32), 256, 0, stream>>>(w_head, Wht, 1024, 1024);
  k_gemm_bt<0><<<dim3(24, 64), 256, 0, stream>>>(Xb, Wqkvt, b_qkv, Qw, Kw, Vtw,
                                                 nullptr, 1024, 3072);
  k_flash<<<1024, 256, 0, stream>>>(Qw, Kw, Vtw, Attn);
  k_gemm_bt<1><<<dim3(8, 64), 256, 0, stream>>>(Attn, Wht, b_head, nullptr, nullptr,
                                                nullptr, out, 1024, 1024);
}

// Round 3
// 164.385 us; speedup vs baseline: 3.2555x; 1.3462x over previous
//
#include <hip/hip_runtime.h>
#include <stdint.h>

typedef __bf16 bf16x8 __attribute__((ext_vector_type(8)));
typedef __bf16 bf16x4 __attribute__((ext_vector_type(4)));
typedef float f32x4 __attribute__((ext_vector_type(4)));
typedef unsigned short u16;

__device__ __forceinline__ u16 f2bf(float f) {
  union { float f; unsigned u; } v; v.f = f;
  return (u16)((v.u + 0x7fffu + ((v.u >> 16) & 1u)) >> 16);
}

#define GLOAD_LDS16(gp, lp)                                                       \
  __builtin_amdgcn_global_load_lds((__attribute__((address_space(1))) void*)(gp), \
                                   (__attribute__((address_space(3))) void*)(lp), \
                                   16, 0, 0)

// ---------------- f32 -> bf16, vectorized ----------------
__global__ void k_cvt_bf16(const float* __restrict__ in, u16* __restrict__ out, int n4) {
  int i = blockIdx.x * blockDim.x + threadIdx.x;
  if (i >= n4) return;
  float4 v = ((const float4*)in)[i];
  ushort4 o;
  o.x = f2bf(v.x); o.y = f2bf(v.y); o.z = f2bf(v.z); o.w = f2bf(v.w);
  ((ushort4*)out)[i] = o;
}

// ---------------- w[K][N] f32 -> wt[N][K] bf16 (tiled transpose) ----------------
__global__ void k_transpose_bf16(const float* __restrict__ w, u16* __restrict__ wt,
                                 int K, int N) {
  __shared__ u16 t[32][33];
  int n0 = blockIdx.x * 32, k0 = blockIdx.y * 32;
  int tx = threadIdx.x & 31, ty = threadIdx.x >> 5;  // ty 0..7
#pragma unroll
  for (int j = 0; j < 4; ++j) {
    int r = ty + j * 8;
    t[r][tx] = f2bf(w[(size_t)(k0 + r) * N + n0 + tx]);
  }
  __syncthreads();
#pragma unroll
  for (int j = 0; j < 4; ++j) {
    int r = ty + j * 8;
    wt[(size_t)(n0 + r) * K + k0 + tx] = t[tx][r];
  }
}

// ---------------- bt-GEMM: C[M][N] = A[M][K]*Bt[N][K]^T + bias ----------------
// MODE 0: QKV epilogue -> scatter Q(,*0.125)/K/[B*H][S][DK], Vt [B*H][DK][S]
// MODE 1: f32 out + bias
template <int MODE>
__global__ void __launch_bounds__(256, 2)
k_gemm_bt(const u16* __restrict__ A, const u16* __restrict__ Bt,
          const float* __restrict__ bias, u16* __restrict__ outQ,
          u16* __restrict__ outK, u16* __restrict__ outVt,
          float* __restrict__ outF, int Kdim, int Ncols) {
  __shared__ u16 Asq[128 * 64];
  __shared__ u16 Bsq[128 * 64];
  const int tid = threadIdx.x;
  const int lane = tid & 63;
  const int wv = tid >> 6;
  const int g = lane >> 4;
  const int lr = lane & 15;
  const int wr = wv >> 1, wc = wv & 1;
  const int row0 = blockIdx.y * 128;
  const int col0 = blockIdx.x * 128;

  const f32x4 fzero = {0.f, 0.f, 0.f, 0.f};
  f32x4 acc[4][4];
#pragma unroll
  for (int m = 0; m < 4; ++m)
#pragma unroll
    for (int n = 0; n < 4; ++n) acc[m][n] = fzero;

  const u16* Arow = A + (size_t)row0 * Kdim;
  const u16* Brow = Bt + (size_t)col0 * Kdim;

  for (int kt = 0; kt < Kdim; kt += 64) {
#pragma unroll
    for (int j = 0; j < 4; ++j) {
      int unit = j * 256 + wv * 64 + lane;
      int r = unit >> 3, u = unit & 7;
      int ug = u ^ (r & 7);
      GLOAD_LDS16(Arow + (size_t)r * Kdim + kt + ug * 8,
                  &Asq[(size_t)(j * 256 + wv * 64) * 8]);
      GLOAD_LDS16(Brow + (size_t)r * Kdim + kt + ug * 8,
                  &Bsq[(size_t)(j * 256 + wv * 64) * 8]);
    }
    __syncthreads();
#pragma unroll
    for (int kc = 0; kc < 2; ++kc) {
      bf16x8 af[4], bfr[4];
#pragma unroll
      for (int m = 0; m < 4; ++m) {
        int r = wr * 64 + m * 16 + lr;
        int u = (kc * 4 + g) ^ (r & 7);
        af[m] = *(const bf16x8*)((const char*)Asq + r * 128 + u * 16);
      }
#pragma unroll
      for (int n = 0; n < 4; ++n) {
        int r = wc * 64 + n * 16 + lr;
        int u = (kc * 4 + g) ^ (r & 7);
        bfr[n] = *(const bf16x8*)((const char*)Bsq + r * 128 + u * 16);
      }
#pragma unroll
      for (int m = 0; m < 4; ++m)
#pragma unroll
        for (int n = 0; n < 4; ++n)
          acc[m][n] = __builtin_amdgcn_mfma_f32_16x16x32_bf16(af[m], bfr[n],
                                                              acc[m][n], 0, 0, 0);
    }
    __syncthreads();
  }

  // epilogue: C/D layout col = lane&15, row = 4*(lane>>4)+reg
#pragma unroll
  for (int n = 0; n < 4; ++n) {
    int e = col0 + wc * 64 + n * 16 + lr;
    float bv = bias[e];
    if (MODE == 0) {
      int part = e >> 10;
      int d = e & 1023;
      int hh = d >> 6;
      int dk = d & 63;
#pragma unroll
      for (int m = 0; m < 4; ++m) {
        int tbase = row0 + wr * 64 + m * 16 + g * 4;
        int bb = tbase >> 11;
        int s = tbase & 2047;
        size_t bh = (size_t)((bb << 4) + hh);
        if (part == 2) {
          ushort4 pk;
          pk.x = f2bf(acc[m][n][0] + bv);
          pk.y = f2bf(acc[m][n][1] + bv);
          pk.z = f2bf(acc[m][n][2] + bv);
          pk.w = f2bf(acc[m][n][3] + bv);
          *(ushort4*)(outVt + (bh * 64 + dk) * 2048 + s) = pk;
        } else {
#pragma unroll
          for (int i = 0; i < 4; ++i) {
            float val = acc[m][n][i] + bv;
            size_t off = (bh * 2048 + (size_t)(s + i)) * 64 + dk;
            if (part == 0)
              outQ[off] = f2bf(val * 0.125f);
            else
              outK[off] = f2bf(val);
          }
        }
      }
    } else {
#pragma unroll
      for (int m = 0; m < 4; ++m)
#pragma unroll
        for (int i = 0; i < 4; ++i) {
          int t = row0 + wr * 64 + m * 16 + g * 4 + i;
          outF[(size_t)t * Ncols + e] = acc[m][n][i] + bv;
        }
    }
  }
}

// ---------------- causal flash attention, swapped-operand (q per lane) ----------------
// grid 1024: block handles q-tiles (qa, 31-qa) of one (b,h) -> uniform work.
// S = mfma(Kfrag, Qfrag): S[row=k-local][col=q-local] -> lane owns q = q0 + (lane&15);
// all softmax state (m, l, alpha) is lane-local scalar; reduce = 2 shfl (xor16/32).
// O = mfma(Vtfrag, Pfrag): O[row=d-local][col=q-local] -> same q-per-lane layout.
// P round-trips per-wave LDS [16 q][64 k] with 16B-unit XOR swizzle (u ^= lr&7).

__device__ __forceinline__ void stage_kv(const u16* __restrict__ Kb,
                                         const u16* __restrict__ Vb, int kbase,
                                         u16* Kbuf, u16* Vbuf, int wv, int lane) {
#pragma unroll
  for (int j = 0; j < 2; ++j) {
    int unit = j * 256 + wv * 64 + lane;
    int r = unit >> 3, u = unit & 7;
    int ug = u ^ (r & 7);
    GLOAD_LDS16(Kb + (size_t)(kbase + r) * 64 + ug * 8, Kbuf + (j * 256 + wv * 64) * 8);
    GLOAD_LDS16(Vb + (size_t)r * 2048 + kbase + ug * 8, Vbuf + (j * 256 + wv * 64) * 8);
  }
}

__device__ __forceinline__ void attn_tile(const u16* Kbuf, const u16* Vbuf, u16* Pw,
                                          const bf16x8* qf, f32x4* o, float& mrow,
                                          float& lrow, int q0, int kbase, int lr,
                                          int g) {
  const f32x4 fzero = {0.f, 0.f, 0.f, 0.f};
  f32x4 s[4];
  __builtin_amdgcn_s_setprio(1);
#pragma unroll
  for (int cf = 0; cf < 4; ++cf) {
    s[cf] = fzero;
#pragma unroll
    for (int kc = 0; kc < 2; ++kc) {
      int r = cf * 16 + lr;
      int us = (kc * 4 + g) ^ (r & 7);
      bf16x8 kf = *(const bf16x8*)(Kbuf + r * 64 + us * 8);
      // swapped: A = K rows, B = Q -> S[k][q], lane owns q = q0+lr
      s[cf] = __builtin_amdgcn_mfma_f32_16x16x32_bf16(kf, qf[kc], s[cf], 0, 0, 0);
    }
  }
  __builtin_amdgcn_s_setprio(0);
  const int q = q0 + lr;
  if (kbase + 63 > q0) {  // diagonal tile: k = kbase + cf*16 + 4g + i
#pragma unroll
    for (int cf = 0; cf < 4; ++cf)
#pragma unroll
      for (int i = 0; i < 4; ++i)
        if (kbase + cf * 16 + 4 * g + i > q) s[cf][i] = -1e30f;
  }
  // lane-local softmax over 16 regs + 2 shfl across the 4 g-groups
  float tm = -1e30f;
#pragma unroll
  for (int cf = 0; cf < 4; ++cf)
#pragma unroll
    for (int i = 0; i < 4; ++i) tm = fmaxf(tm, s[cf][i]);
  tm = fmaxf(tm, __shfl_xor(tm, 16));
  tm = fmaxf(tm, __shfl_xor(tm, 32));
  if (__all(tm - mrow <= 8.f)) {  // T13 defer-max: skip rescale, P bounded by e^8
    float rs = 0.f;
#pragma unroll
    for (int cf = 0; cf < 4; ++cf)
#pragma unroll
      for (int i = 0; i < 4; ++i) {
        s[cf][i] = __expf(s[cf][i] - mrow);
        rs += s[cf][i];
      }
    rs += __shfl_xor(rs, 16);
    rs += __shfl_xor(rs, 32);
    lrow += rs;
  } else {
    float mn = fmaxf(mrow, tm);
    float alpha = __expf(mrow - mn);
    mrow = mn;
    float rs = 0.f;
#pragma unroll
    for (int cf = 0; cf < 4; ++cf)
#pragma unroll
      for (int i = 0; i < 4; ++i) {
        s[cf][i] = __expf(s[cf][i] - mn);
        rs += s[cf][i];
      }
    rs += __shfl_xor(rs, 16);
    rs += __shfl_xor(rs, 32);
    lrow = lrow * alpha + rs;
#pragma unroll
    for (int cf = 0; cf < 4; ++cf)
#pragma unroll
      for (int i = 0; i < 4; ++i) o[cf][i] *= alpha;
  }
  // P write: lane has P[q=lr][k=16cf+4g+i] -> 4x ds_write_b64, swizzled 16B units
#pragma unroll
  for (int cf = 0; cf < 4; ++cf) {
    bf16x4 ph;
    ph[0] = (__bf16)s[cf][0];
    ph[1] = (__bf16)s[cf][1];
    ph[2] = (__bf16)s[cf][2];
    ph[3] = (__bf16)s[cf][3];
    int uw = (2 * cf + (g >> 1)) ^ (lr & 7);
    *(bf16x4*)(Pw + lr * 64 + uw * 8 + (g & 1) * 4) = ph;
  }
  // PV: A = Vt rows (d), B = P cols (q) -> O[d][q]
  __builtin_amdgcn_s_setprio(1);
#pragma unroll
  for (int kc = 0; kc < 2; ++kc) {
    int ur = (4 * kc + g) ^ (lr & 7);
    bf16x8 pb = *(const bf16x8*)(Pw + lr * 64 + ur * 8);
#pragma unroll
    for (int cf = 0; cf < 4; ++cf) {
      int r = cf * 16 + lr;
      int us = (kc * 4 + g) ^ (r & 7);
      bf16x8 vf = *(const bf16x8*)(Vbuf + r * 64 + us * 8);
      o[cf] = __builtin_amdgcn_mfma_f32_16x16x32_bf16(vf, pb, o[cf], 0, 0, 0);
    }
  }
  __builtin_amdgcn_s_setprio(0);
}

__global__ void __launch_bounds__(256, 4)
k_flash(const u16* __restrict__ Qg, const u16* __restrict__ Kg,
        const u16* __restrict__ Vtg, u16* __restrict__ attn) {
  __shared__ u16 KV[2][2][4096];       // [buf][K/V][64 rows x 64 cols swizzled]
  __shared__ u16 P_lds[4][16][64];     // per-wave P, 16B-unit XOR swizzle
  const int tid = threadIdx.x;
  const int lane = tid & 63;
  const int wv = tid >> 6;
  const int g = lane >> 4;
  const int lr = lane & 15;

  // XCD-chunked bijective swizzle: 1024 blocks, 8 XCDs, 128/chunk
  const int flat = blockIdx.x;
  const int swz = (flat & 7) * 128 + (flat >> 3);
  const int qa_t = swz & 15;           // 0..15
  const int qb_t = 31 - qa_t;          // 16..31
  const int bh = swz >> 4;

  const u16* Qb = Qg + (size_t)bh * 2048 * 64;
  const u16* Kb = Kg + (size_t)bh * 2048 * 64;
  const u16* Vb = Vtg + (size_t)bh * 64 * 2048;
  u16* Pw = &P_lds[wv][0][0];

  const int q0a = qa_t * 64 + wv * 16;
  const int q0b = qb_t * 64 + wv * 16;

  bf16x8 qfa[2], qfb[2];
#pragma unroll
  for (int kc = 0; kc < 2; ++kc) {
    qfa[kc] = *(const bf16x8*)(Qb + (size_t)(q0a + lr) * 64 + kc * 32 + g * 8);
    qfb[kc] = *(const bf16x8*)(Qb + (size_t)(q0b + lr) * 64 + kc * 32 + g * 8);
  }

  const f32x4 fzero = {0.f, 0.f, 0.f, 0.f};
  f32x4 oa[4], ob[4];
#pragma unroll
  for (int cf = 0; cf < 4; ++cf) { oa[cf] = fzero; ob[cf] = fzero; }
  float mra = -1e30f, lra = 0.f, mrb = -1e30f, lrb = 0.f;

  stage_kv(Kb, Vb, 0, &KV[0][0][0], &KV[0][1][0], wv, lane);
  __syncthreads();

  for (int kt = 0; kt <= qb_t; ++kt) {
    const int nb = kt & 1;
    const u16* Kbuf = &KV[nb][0][0];
    const u16* Vbuf = &KV[nb][1][0];
    if (kt < qb_t)
      stage_kv(Kb, Vb, (kt + 1) * 64, &KV[nb ^ 1][0][0], &KV[nb ^ 1][1][0], wv, lane);
    attn_tile(Kbuf, Vbuf, Pw, qfb, ob, mrb, lrb, q0b, kt * 64, lr, g);
    if (kt <= qa_t)
      attn_tile(Kbuf, Vbuf, Pw, qfa, oa, mra, lra, q0a, kt * 64, lr, g);
    __syncthreads();
  }

  // epilogue: lane owns q = q0+lr; o[cf][i] is d = cf*16 + 4g + i -> ushort4 stores
  const int bb = bh >> 4, hh = bh & 15;
  const float inv_a = 1.f / lra, inv_b = 1.f / lrb;
#pragma unroll
  for (int cf = 0; cf < 4; ++cf) {
    ushort4 pa, pb;
    pa.x = f2bf(oa[cf][0] * inv_a); pa.y = f2bf(oa[cf][1] * inv_a);
    pa.z = f2bf(oa[cf][2] * inv_a); pa.w = f2bf(oa[cf][3] * inv_a);
    pb.x = f2bf(ob[cf][0] * inv_b); pb.y = f2bf(ob[cf][1] * inv_b);
    pb.z = f2bf(ob[cf][2] * inv_b); pb.w = f2bf(ob[cf][3] * inv_b);
    size_t dcol = hh * 64 + cf * 16 + 4 * g;
    *(ushort4*)(attn + ((size_t)(bb * 2048 + q0a + lr)) * 1024 + dcol) = pa;
    *(ushort4*)(attn + ((size_t)(bb * 2048 + q0b + lr)) * 1024 + dcol) = pb;
  }
}

extern "C" void kernel_launch(void* const* d_in, const int* in_sizes, int n_in,
                              void* d_out, int out_size, void* d_ws, size_t ws_size,
                              hipStream_t stream) {
  const float* x      = (const float*)d_in[0];
  // d_in[1] = mask: exactly causal triu(-1e9) -> applied analytically, not read
  const float* w_qkv  = (const float*)d_in[2];
  const float* b_qkv  = (const float*)d_in[3];
  const float* w_head = (const float*)d_in[4];
  const float* b_head = (const float*)d_in[5];
  float* out = (float*)d_out;

  u16* Xb    = (u16*)d_ws;                      // 8192*1024 bf16
  u16* Wqkvt = Xb + (size_t)8192 * 1024;        // 3072*1024
  u16* Wht   = Wqkvt + (size_t)3072 * 1024;     // 1024*1024
  u16* Qw    = Wht + (size_t)1024 * 1024;       // 64*2048*64
  u16* Kw    = Qw + (size_t)64 * 2048 * 64;
  u16* Vtw   = Kw + (size_t)64 * 2048 * 64;
  u16* Attn  = Xb;  // alias: Xb dead after GEMM1

  k_cvt_bf16<<<8192, 256, 0, stream>>>(x, Xb, (8192 * 1024) / 4);
  k_transpose_bf16<<<dim3(96, 32), 256, 0, stream>>>(w_qkv, Wqkvt, 1024, 3072);
  k_transpose_bf16<<<dim3(32, 32), 256, 0, stream>>>(w_head, Wht, 1024, 1024);
  k_gemm_bt<0><<<dim3(24, 64), 256, 0, stream>>>(Xb, Wqkvt, b_qkv, Qw, Kw, Vtw,
                                                 nullptr, 1024, 3072);
  k_flash<<<1024, 256, 0, stream>>>(Qw, Kw, Vtw, Attn);
  k_gemm_bt<1><<<dim3(8, 64), 256, 0, stream>>>(Attn, Wht, b_head, nullptr, nullptr,
                                                nullptr, out, 1024, 1024);
}